// Round 2
// baseline (1655.828 us; speedup 1.0000x reference)
//
#include <hip/hip_runtime.h>
#include <hip/hip_bf16.h>
#include <stdint.h>

#define S_LEN  2048
#define DMODEL 2048
#define NBATCH 2
#define NHEADS 16
#define DHEAD  128
#define HID    8192
#define NROWS  4096   // NBATCH * S_LEN

typedef unsigned short u16;
typedef unsigned int   u32;
typedef __attribute__((ext_vector_type(8))) short s16x8;   // 8 bf16 = MFMA A/B frag
typedef __attribute__((ext_vector_type(4))) float f32x4;   // MFMA C/D frag

static __device__ __forceinline__ float bf2f(u16 b) {
  return __uint_as_float(((u32)b) << 16);
}
static __device__ __forceinline__ u16 f2bf(float f) {
  u32 u = __float_as_uint(f);
  return (u16)((u + 0x7fffu + ((u >> 16) & 1u)) >> 16);   // RNE
}

// async global->LDS, 16B per lane; proper addrspacecast (NOT bit-truncation)
static __device__ __forceinline__ void gload16(const void* gp, void* lp) {
  __builtin_amdgcn_global_load_lds(
      (const __attribute__((address_space(1))) void*)gp,
      (__attribute__((address_space(3))) void*)lp, 16, 0, 0);
}

// ---------------------------------------------------------------------------
// Weight prep: W[K][N] f32  ->  Wt[N][K] bf16 (tiled transpose via LDS)
// ---------------------------------------------------------------------------
__global__ __launch_bounds__(256) void transpose_cvt(const float* __restrict__ W,
                                                     u16* __restrict__ Wt,
                                                     int K, int N) {
  __shared__ float tile[32][33];
  const int tx = threadIdx.x, ty = threadIdx.y;       // 32 x 8
  const int n0 = blockIdx.x * 32, k0 = blockIdx.y * 32;
#pragma unroll
  for (int i = 0; i < 4; ++i)
    tile[ty + i * 8][tx] = W[(size_t)(k0 + ty + i * 8) * N + n0 + tx];
  __syncthreads();
#pragma unroll
  for (int i = 0; i < 4; ++i)
    Wt[(size_t)(n0 + ty + i * 8) * K + k0 + tx] = f2bf(tile[tx][ty + i * 8]);
}

// ---------------------------------------------------------------------------
// RMSNorm: row of f32 [DMODEL] -> bf16, one block per row
// ---------------------------------------------------------------------------
__global__ __launch_bounds__(256) void rmsnorm_k(const float* __restrict__ x,
                                                 const float* __restrict__ g,
                                                 u16* __restrict__ out) {
  const int row = blockIdx.x;
  const int tid = threadIdx.x;
  const float4* xr = (const float4*)(x + (size_t)row * DMODEL);
  float4 v0 = xr[tid];
  float4 v1 = xr[tid + 256];
  float ss = v0.x * v0.x + v0.y * v0.y + v0.z * v0.z + v0.w * v0.w +
             v1.x * v1.x + v1.y * v1.y + v1.z * v1.z + v1.w * v1.w;
#pragma unroll
  for (int o = 1; o < 64; o <<= 1) ss += __shfl_xor(ss, o);
  __shared__ float red[4];
  if ((tid & 63) == 0) red[tid >> 6] = ss;
  __syncthreads();
  const float tot = red[0] + red[1] + red[2] + red[3];
  const float rms = rsqrtf(tot * (1.0f / DMODEL) + 1e-6f);
  const float4* gr = (const float4*)g;
  float4 g0 = gr[tid], g1 = gr[tid + 256];
  ushort4 o0, o1;
  o0.x = f2bf(v0.x * rms * g0.x); o0.y = f2bf(v0.y * rms * g0.y);
  o0.z = f2bf(v0.z * rms * g0.z); o0.w = f2bf(v0.w * rms * g0.w);
  o1.x = f2bf(v1.x * rms * g1.x); o1.y = f2bf(v1.y * rms * g1.y);
  o1.z = f2bf(v1.z * rms * g1.z); o1.w = f2bf(v1.w * rms * g1.w);
  ushort4* orow = (ushort4*)(out + (size_t)row * DMODEL);
  orow[tid] = o0;
  orow[tid + 256] = o1;
}

// ---------------------------------------------------------------------------
// GEMM: C[M,N] = A[M,K](bf16) * Bt[N,K](bf16)^T ; m97 structure (128x128, BK=32)
// EPI 0: store bf16 [M,N]
// EPI 1: store bf16 to Vt[b,h,dh,s] layout (for attention PV operand)
// EPI 2: store f32 [M,N] = acc + resid
// ---------------------------------------------------------------------------
template <int EPI>
__global__ __launch_bounds__(256) void gemm_bt(const u16* __restrict__ A,
                                               const u16* __restrict__ Bt,
                                               void* __restrict__ C,
                                               const float* __restrict__ resid,
                                               int M, int N, int K) {
  __shared__ u16 As[128 * 32];
  __shared__ u16 Bs[128 * 32];
  const int tid = threadIdx.x;
  const int lane = tid & 63, wave = tid >> 6;
  const int m0 = blockIdx.y << 7, n0 = blockIdx.x << 7;
  const int wr = wave >> 1, wc = wave & 1;

  const f32x4 fz = {0.f, 0.f, 0.f, 0.f};
  f32x4 acc[4][4];
#pragma unroll
  for (int i = 0; i < 4; ++i)
#pragma unroll
    for (int j = 0; j < 4; ++j) acc[i][j] = fz;

  // staging: 16 chunks of 1KB (A:8, B:8); wave w does A/B chunks 2w, 2w+1
  const int cA = wave * 2;
  const int srow = cA * 16 + (lane >> 2);      // row of this lane's 16B piece
  const int scol = (lane & 3) * 8;             // bf16 col within BK=32
  const u16* gA0 = A + (size_t)(m0 + srow) * K + scol;
  const u16* gA1 = A + (size_t)(m0 + srow + 16) * K + scol;
  const u16* gB0 = Bt + (size_t)(n0 + srow) * K + scol;
  const u16* gB1 = Bt + (size_t)(n0 + srow + 16) * K + scol;
  u16* lA0 = &As[cA * 512];
  u16* lA1 = &As[cA * 512 + 512];
  u16* lB0 = &Bs[cA * 512];
  u16* lB1 = &Bs[cA * 512 + 512];

  const u16* pa = &As[(size_t)(wr * 64 + (lane & 15)) * 32 + (lane >> 4) * 8];
  const u16* pb = &Bs[(size_t)(wc * 64 + (lane & 15)) * 32 + (lane >> 4) * 8];

  for (int kt = 0; kt < K; kt += 32) {
    __syncthreads();
    gload16(gA0 + kt, lA0);
    gload16(gA1 + kt, lA1);
    gload16(gB0 + kt, lB0);
    gload16(gB1 + kt, lB1);
    __syncthreads();
    s16x8 ar[4], br[4];
#pragma unroll
    for (int m = 0; m < 4; ++m) ar[m] = *(const s16x8*)(pa + m * 16 * 32);
#pragma unroll
    for (int n = 0; n < 4; ++n) br[n] = *(const s16x8*)(pb + n * 16 * 32);
#pragma unroll
    for (int m = 0; m < 4; ++m)
#pragma unroll
      for (int n = 0; n < 4; ++n)
        acc[m][n] = __builtin_amdgcn_mfma_f32_16x16x32_bf16(ar[m], br[n],
                                                            acc[m][n], 0, 0, 0);
  }

  // C/D layout (m89-verified): col = lane&15, row = (lane>>4)*4 + reg
  const int orow = m0 + wr * 64 + ((lane >> 4) << 2);
  const int ocol = n0 + wc * 64 + (lane & 15);
  if (EPI == 0) {
    u16* O = (u16*)C;
#pragma unroll
    for (int m = 0; m < 4; ++m)
#pragma unroll
      for (int n = 0; n < 4; ++n)
#pragma unroll
        for (int r = 0; r < 4; ++r)
          O[(size_t)(orow + m * 16 + r) * N + ocol + n * 16] = f2bf(acc[m][n][r]);
  } else if (EPI == 1) {
    u16* O = (u16*)C;
#pragma unroll
    for (int m = 0; m < 4; ++m) {
      const int row = orow + m * 16;            // (b, s); r spans s..s+3
      const int b = row >> 11, s = row & 2047;
#pragma unroll
      for (int n = 0; n < 4; ++n) {
        const int col = ocol + n * 16;          // h*128 + dh
        const int hh = col >> 7, dd = col & 127;
        ushort4 o;
        o.x = f2bf(acc[m][n][0]); o.y = f2bf(acc[m][n][1]);
        o.z = f2bf(acc[m][n][2]); o.w = f2bf(acc[m][n][3]);
        *(ushort4*)(O + (((size_t)(b * NHEADS + hh) * DHEAD + dd) << 11) + s) = o;
      }
    }
  } else {
    float* O = (float*)C;
#pragma unroll
    for (int m = 0; m < 4; ++m)
#pragma unroll
      for (int n = 0; n < 4; ++n)
#pragma unroll
        for (int r = 0; r < 4; ++r) {
          const size_t idx = (size_t)(orow + m * 16 + r) * N + ocol + n * 16;
          O[idx] = acc[m][n][r] + resid[idx];
        }
  }
}

// ---------------------------------------------------------------------------
// Fused SwiGLU GEMM: U[M,N] = bf16( silu(A·B1t^T) * (A·B3t^T) )
// Same 128x128/BK=32 structure, two B operands sharing the A tile.
// ---------------------------------------------------------------------------
__global__ __launch_bounds__(256) void gemm_swiglu(const u16* __restrict__ A,
                                                   const u16* __restrict__ B1t,
                                                   const u16* __restrict__ B3t,
                                                   u16* __restrict__ U,
                                                   int M, int N, int K) {
  __shared__ u16 As[128 * 32];
  __shared__ u16 Bs1[128 * 32];
  __shared__ u16 Bs3[128 * 32];
  const int tid = threadIdx.x;
  const int lane = tid & 63, wave = tid >> 6;
  const int m0 = blockIdx.y << 7, n0 = blockIdx.x << 7;
  const int wr = wave >> 1, wc = wave & 1;

  const f32x4 fz = {0.f, 0.f, 0.f, 0.f};
  f32x4 acc1[4][4], acc3[4][4];
#pragma unroll
  for (int i = 0; i < 4; ++i)
#pragma unroll
    for (int j = 0; j < 4; ++j) { acc1[i][j] = fz; acc3[i][j] = fz; }

  const int cA = wave * 2;
  const int srow = cA * 16 + (lane >> 2);
  const int scol = (lane & 3) * 8;
  const u16* gA0 = A + (size_t)(m0 + srow) * K + scol;
  const u16* gA1 = A + (size_t)(m0 + srow + 16) * K + scol;
  const u16* gB10 = B1t + (size_t)(n0 + srow) * K + scol;
  const u16* gB11 = B1t + (size_t)(n0 + srow + 16) * K + scol;
  const u16* gB30 = B3t + (size_t)(n0 + srow) * K + scol;
  const u16* gB31 = B3t + (size_t)(n0 + srow + 16) * K + scol;
  u16* lA0 = &As[cA * 512];
  u16* lA1 = &As[cA * 512 + 512];
  u16* lB10 = &Bs1[cA * 512];
  u16* lB11 = &Bs1[cA * 512 + 512];
  u16* lB30 = &Bs3[cA * 512];
  u16* lB31 = &Bs3[cA * 512 + 512];

  const u16* pa = &As[(size_t)(wr * 64 + (lane & 15)) * 32 + (lane >> 4) * 8];
  const u16* pb1 = &Bs1[(size_t)(wc * 64 + (lane & 15)) * 32 + (lane >> 4) * 8];
  const u16* pb3 = &Bs3[(size_t)(wc * 64 + (lane & 15)) * 32 + (lane >> 4) * 8];

  for (int kt = 0; kt < K; kt += 32) {
    __syncthreads();
    gload16(gA0 + kt, lA0);
    gload16(gA1 + kt, lA1);
    gload16(gB10 + kt, lB10);
    gload16(gB11 + kt, lB11);
    gload16(gB30 + kt, lB30);
    gload16(gB31 + kt, lB31);
    __syncthreads();
    s16x8 ar[4], b1[4], b3[4];
#pragma unroll
    for (int m = 0; m < 4; ++m) ar[m] = *(const s16x8*)(pa + m * 16 * 32);
#pragma unroll
    for (int n = 0; n < 4; ++n) b1[n] = *(const s16x8*)(pb1 + n * 16 * 32);
#pragma unroll
    for (int n = 0; n < 4; ++n) b3[n] = *(const s16x8*)(pb3 + n * 16 * 32);
#pragma unroll
    for (int m = 0; m < 4; ++m)
#pragma unroll
      for (int n = 0; n < 4; ++n) {
        acc1[m][n] = __builtin_amdgcn_mfma_f32_16x16x32_bf16(ar[m], b1[n],
                                                             acc1[m][n], 0, 0, 0);
        acc3[m][n] = __builtin_amdgcn_mfma_f32_16x16x32_bf16(ar[m], b3[n],
                                                             acc3[m][n], 0, 0, 0);
      }
  }

  const int orow = m0 + wr * 64 + ((lane >> 4) << 2);
  const int ocol = n0 + wc * 64 + (lane & 15);
#pragma unroll
  for (int m = 0; m < 4; ++m)
#pragma unroll
    for (int n = 0; n < 4; ++n)
#pragma unroll
      for (int r = 0; r < 4; ++r) {
        const float a = acc1[m][n][r];
        const float u = (a / (1.f + __expf(-a))) * acc3[m][n][r];
        U[(size_t)(orow + m * 16 + r) * N + ocol + n * 16] = f2bf(u);
      }
}

// ---------------------------------------------------------------------------
// RoPE tables: cos/sin [S_LEN][64] f32
// ---------------------------------------------------------------------------
__global__ __launch_bounds__(256) void rope_table_k(float* __restrict__ tc,
                                                    float* __restrict__ ts) {
  const int idx = blockIdx.x * 256 + threadIdx.x;   // S_LEN*64 = 131072
  const int pos = idx >> 6, j = idx & 63;
  const float inv = expf(((float)(2 * j) * (1.0f / 128.0f)) * -logf(10000.0f));
  const float th = (float)pos * inv;
  tc[idx] = cosf(th);
  ts[idx] = sinf(th);
}

// RoPE apply, in place on Q and K ([NROWS][DMODEL] bf16)
__global__ __launch_bounds__(256) void rope_apply_k(u16* __restrict__ Q,
                                                    u16* __restrict__ Kb,
                                                    const float* __restrict__ tc,
                                                    const float* __restrict__ ts) {
  const int idx = blockIdx.x * 256 + threadIdx.x;   // 2 * 4096 * 16 * 64 = 2^23
  const int j = idx & 63;
  const int h = (idx >> 6) & (NHEADS - 1);
  const int row = (idx >> 10) & (NROWS - 1);
  u16* P = (idx >> 22) ? Kb : Q;
  const int s = row & (S_LEN - 1);
  const float c = tc[s * 64 + j], sn = ts[s * 64 + j];
  const size_t base = (size_t)row * DMODEL + h * DHEAD;
  const float x1 = bf2f(P[base + j]);
  const float x2 = bf2f(P[base + 64 + j]);
  P[base + j]      = f2bf(x1 * c - x2 * sn);
  P[base + 64 + j] = f2bf(x2 * c + x1 * sn);
}

// ---------------------------------------------------------------------------
// Flash attention (non-causal). Block = 4 waves, each wave owns 16 q-rows.
// Q,K: [NROWS][DMODEL] bf16 (roped); Vt: [B*H][DHEAD][S_LEN] bf16; O like Q.
// ---------------------------------------------------------------------------
__global__ __launch_bounds__(256) void attn_k(const u16* __restrict__ Q,
                                              const u16* __restrict__ Kb,
                                              const u16* __restrict__ Vt,
                                              u16* __restrict__ O) {
  __shared__ __align__(16) u16 Plds[4][16][32];   // per-wave P tile
  const int tid = threadIdx.x, lane = tid & 63, wave = tid >> 6;
  const int qt = blockIdx.x, bh = blockIdx.y;
  const int b = bh >> 4, h = bh & 15;
  const int q0 = qt * 64 + wave * 16;

  // Q fragments: A[row=lane&15][k = ks*32 + 8*(lane>>4) + j]
  const size_t qoff = (size_t)(b * S_LEN + q0 + (lane & 15)) * DMODEL +
                      h * DHEAD + (lane >> 4) * 8;
  s16x8 aq[4];
#pragma unroll
  for (int ks = 0; ks < 4; ++ks) aq[ks] = *(const s16x8*)(Q + qoff + ks * 32);

  const float scale = 0.08838834764831845f;  // 1/sqrt(128)
  const f32x4 fz = {0.f, 0.f, 0.f, 0.f};
  f32x4 ctx[8];
#pragma unroll
  for (int n = 0; n < 8; ++n) ctx[n] = fz;
  float mrow[4] = {-1e30f, -1e30f, -1e30f, -1e30f};
  float lrow[4] = {0.f, 0.f, 0.f, 0.f};

  const size_t kbase = (size_t)(b * S_LEN) * DMODEL + h * DHEAD + (lane >> 4) * 8;
  const size_t vbase = (size_t)bh * DHEAD * S_LEN + (lane >> 4) * 8;

  for (int kv = 0; kv < S_LEN; kv += 32) {
    f32x4 s0 = fz, s1 = fz;
#pragma unroll
    for (int ks = 0; ks < 4; ++ks) {
      s16x8 k0 = *(const s16x8*)(Kb + kbase + (size_t)(kv + (lane & 15)) * DMODEL + ks * 32);
      s16x8 k1 = *(const s16x8*)(Kb + kbase + (size_t)(kv + 16 + (lane & 15)) * DMODEL + ks * 32);
      s0 = __builtin_amdgcn_mfma_f32_16x16x32_bf16(aq[ks], k0, s0, 0, 0, 0);
      s1 = __builtin_amdgcn_mfma_f32_16x16x32_bf16(aq[ks], k1, s1, 0, 0, 0);
    }
    float p0[4], p1[4], corr[4];
#pragma unroll
    for (int r = 0; r < 4; ++r) {
      const float a0 = s0[r] * scale, a1 = s1[r] * scale;
      float v = fmaxf(a0, a1);
#pragma unroll
      for (int o = 1; o < 16; o <<= 1) v = fmaxf(v, __shfl_xor(v, o));
      const float nm = fmaxf(mrow[r], v);
      corr[r] = __expf(mrow[r] - nm);
      mrow[r] = nm;
      p0[r] = __expf(a0 - nm);
      p1[r] = __expf(a1 - nm);
      float rs = p0[r] + p1[r];
#pragma unroll
      for (int o = 1; o < 16; o <<= 1) rs += __shfl_xor(rs, o);
      lrow[r] = lrow[r] * corr[r] + rs;
    }
#pragma unroll
    for (int n = 0; n < 8; ++n)
#pragma unroll
      for (int r = 0; r < 4; ++r) ctx[n][r] *= corr[r];
    // redistribute P via per-wave LDS (C-layout rows -> A-layout rows)
#pragma unroll
    for (int r = 0; r < 4; ++r) {
      Plds[wave][(lane >> 4) * 4 + r][lane & 15] = f2bf(p0[r]);
      Plds[wave][(lane >> 4) * 4 + r][16 + (lane & 15)] = f2bf(p1[r]);
    }
    const s16x8 pa = *(const s16x8*)&Plds[wave][lane & 15][(lane >> 4) * 8];
#pragma unroll
    for (int n = 0; n < 8; ++n) {
      s16x8 bv = *(const s16x8*)(Vt + vbase + (size_t)(n * 16 + (lane & 15)) * S_LEN + kv);
      ctx[n] = __builtin_amdgcn_mfma_f32_16x16x32_bf16(pa, bv, ctx[n], 0, 0, 0);
    }
  }

  float inv[4];
#pragma unroll
  for (int r = 0; r < 4; ++r) inv[r] = 1.0f / lrow[r];
#pragma unroll
  for (int n = 0; n < 8; ++n)
#pragma unroll
    for (int r = 0; r < 4; ++r)
      O[(size_t)(b * S_LEN + q0 + (lane >> 4) * 4 + r) * DMODEL +
        h * DHEAD + n * 16 + (lane & 15)] = f2bf(ctx[n][r] * inv[r]);
}

// ---------------------------------------------------------------------------
extern "C" void kernel_launch(void* const* d_in, const int* in_sizes, int n_in,
                              void* d_out, int out_size, void* d_ws, size_t ws_size,
                              hipStream_t stream) {
  (void)in_sizes; (void)n_in; (void)out_size; (void)ws_size;
  const float* x  = (const float*)d_in[0];
  const float* wq = (const float*)d_in[1];
  const float* wk = (const float*)d_in[2];
  const float* wv = (const float*)d_in[3];
  const float* wo = (const float*)d_in[4];
  const float* g1 = (const float*)d_in[5];
  const float* g2 = (const float*)d_in[6];
  const float* w1 = (const float*)d_in[7];
  const float* w2 = (const float*)d_in[8];   // dict order: w1, w2, w3
  const float* w3 = (const float*)d_in[9];
  float* out = (float*)d_out;

  char* ws = (char*)d_ws;
  size_t off = 0;
  auto alloc = [&](size_t bytes) -> char* {
    char* p = ws + off;
    off += (bytes + 255) & ~(size_t)255;
    return p;
  };
  // Layout so that U (64 MB) can alias the dead WQT..VT span.
  u16* WQT = (u16*)alloc((size_t)DMODEL * DMODEL * 2);   //  8 MB
  u16* WKT = (u16*)alloc((size_t)DMODEL * DMODEL * 2);   //  8 MB
  u16* WVT = (u16*)alloc((size_t)DMODEL * DMODEL * 2);   //  8 MB
  u16* WOT = (u16*)alloc((size_t)DMODEL * DMODEL * 2);   //  8 MB
  u16* QB  = (u16*)alloc((size_t)NROWS * DMODEL * 2);    // 16 MB
  u16* KB  = (u16*)alloc((size_t)NROWS * DMODEL * 2);    // 16 MB
  u16* VT  = (u16*)alloc((size_t)NROWS * DMODEL * 2);    // 16 MB
  u16* W1T = (u16*)alloc((size_t)HID * DMODEL * 2);      // 32 MB
  u16* W3T = (u16*)alloc((size_t)HID * DMODEL * 2);      // 32 MB
  u16* W2T = (u16*)alloc((size_t)DMODEL * HID * 2);      // 32 MB
  u16* Hb  = (u16*)alloc((size_t)NROWS * DMODEL * 2);    // 16 MB (h1 / AO / h2)
  float* X1 = (float*)alloc((size_t)NROWS * DMODEL * 4); // 32 MB
  float* TC = (float*)alloc((size_t)S_LEN * 64 * 4);
  float* TS = (float*)alloc((size_t)S_LEN * 64 * 4);
  // U[4096][8192] bf16 = 64 MB aliases WQT..WOT+QB+KB (all dead by then)
  u16* U = WQT;
  u16* AO = Hb;   // attention output overwrites h1 (dead after QKV GEMMs)

  const dim3 b256(256);
  const dim3 tb(32, 8);

  rope_table_k<<<dim3(512), b256, 0, stream>>>(TC, TS);
  transpose_cvt<<<dim3(64, 64), tb, 0, stream>>>(wq, WQT, DMODEL, DMODEL);
  transpose_cvt<<<dim3(64, 64), tb, 0, stream>>>(wk, WKT, DMODEL, DMODEL);
  transpose_cvt<<<dim3(64, 64), tb, 0, stream>>>(wv, WVT, DMODEL, DMODEL);
  transpose_cvt<<<dim3(64, 64), tb, 0, stream>>>(wo, WOT, DMODEL, DMODEL);
  transpose_cvt<<<dim3(256, 64), tb, 0, stream>>>(w1, W1T, DMODEL, HID);
  transpose_cvt<<<dim3(256, 64), tb, 0, stream>>>(w3, W3T, DMODEL, HID);
  transpose_cvt<<<dim3(64, 256), tb, 0, stream>>>(w2, W2T, HID, DMODEL);

  rmsnorm_k<<<dim3(NROWS), b256, 0, stream>>>(x, g1, Hb);
  gemm_bt<0><<<dim3(16, 32), b256, 0, stream>>>(Hb, WQT, QB, nullptr, NROWS, DMODEL, DMODEL);
  gemm_bt<0><<<dim3(16, 32), b256, 0, stream>>>(Hb, WKT, KB, nullptr, NROWS, DMODEL, DMODEL);
  gemm_bt<1><<<dim3(16, 32), b256, 0, stream>>>(Hb, WVT, VT, nullptr, NROWS, DMODEL, DMODEL);
  rope_apply_k<<<dim3(32768), b256, 0, stream>>>(QB, KB, TC, TS);
  attn_k<<<dim3(32, 32), b256, 0, stream>>>(QB, KB, VT, AO);
  gemm_bt<2><<<dim3(16, 32), b256, 0, stream>>>(AO, WOT, X1, x, NROWS, DMODEL, DMODEL);

  rmsnorm_k<<<dim3(NROWS), b256, 0, stream>>>(X1, g2, Hb);
  gemm_swiglu<<<dim3(64, 32), b256, 0, stream>>>(Hb, W1T, W3T, U, NROWS, HID, DMODEL);
  gemm_bt<2><<<dim3(16, 32), b256, 0, stream>>>(U, W2T, out, X1, NROWS, DMODEL, HID);
}

// Round 3
// 1358.300 us; speedup vs baseline: 1.2190x; 1.2190x over previous
//
#include <hip/hip_runtime.h>
#include <hip/hip_bf16.h>
#include <stdint.h>

#define S_LEN  2048
#define DMODEL 2048
#define NBATCH 2
#define NHEADS 16
#define DHEAD  128
#define HID    8192
#define NROWS  4096   // NBATCH * S_LEN

typedef unsigned short u16;
typedef unsigned int   u32;
typedef __attribute__((ext_vector_type(8))) short s16x8;   // 8 bf16 = MFMA A/B frag
typedef __attribute__((ext_vector_type(4))) float f32x4;   // MFMA C/D frag

static __device__ __forceinline__ float bf2f(u16 b) {
  return __uint_as_float(((u32)b) << 16);
}
static __device__ __forceinline__ u16 f2bf(float f) {
  u32 u = __float_as_uint(f);
  return (u16)((u + 0x7fffu + ((u >> 16) & 1u)) >> 16);   // RNE
}

// async global->LDS, 16B per lane; proper addrspacecast
static __device__ __forceinline__ void gload16(const void* gp, void* lp) {
  __builtin_amdgcn_global_load_lds(
      (const __attribute__((address_space(1))) void*)gp,
      (__attribute__((address_space(3))) void*)lp, 16, 0, 0);
}

// ---------------------------------------------------------------------------
// Weight prep: W[K][N] f32  ->  Wt[N][K] bf16 (tiled transpose via LDS)
// ---------------------------------------------------------------------------
__global__ __launch_bounds__(256) void transpose_cvt(const float* __restrict__ W,
                                                     u16* __restrict__ Wt,
                                                     int K, int N) {
  __shared__ float tile[32][33];
  const int tx = threadIdx.x, ty = threadIdx.y;       // 32 x 8
  const int n0 = blockIdx.x * 32, k0 = blockIdx.y * 32;
#pragma unroll
  for (int i = 0; i < 4; ++i)
    tile[ty + i * 8][tx] = W[(size_t)(k0 + ty + i * 8) * N + n0 + tx];
  __syncthreads();
#pragma unroll
  for (int i = 0; i < 4; ++i)
    Wt[(size_t)(n0 + ty + i * 8) * K + k0 + tx] = f2bf(tile[tx][ty + i * 8]);
}

// ---------------------------------------------------------------------------
// RMSNorm: row of f32 [DMODEL] -> bf16, one block per row
// ---------------------------------------------------------------------------
__global__ __launch_bounds__(256) void rmsnorm_k(const float* __restrict__ x,
                                                 const float* __restrict__ g,
                                                 u16* __restrict__ out) {
  const int row = blockIdx.x;
  const int tid = threadIdx.x;
  const float4* xr = (const float4*)(x + (size_t)row * DMODEL);
  float4 v0 = xr[tid];
  float4 v1 = xr[tid + 256];
  float ss = v0.x * v0.x + v0.y * v0.y + v0.z * v0.z + v0.w * v0.w +
             v1.x * v1.x + v1.y * v1.y + v1.z * v1.z + v1.w * v1.w;
#pragma unroll
  for (int o = 1; o < 64; o <<= 1) ss += __shfl_xor(ss, o);
  __shared__ float red[4];
  if ((tid & 63) == 0) red[tid >> 6] = ss;
  __syncthreads();
  const float tot = red[0] + red[1] + red[2] + red[3];
  const float rms = rsqrtf(tot * (1.0f / DMODEL) + 1e-6f);
  const float4* gr = (const float4*)g;
  float4 g0 = gr[tid], g1 = gr[tid + 256];
  ushort4 o0, o1;
  o0.x = f2bf(v0.x * rms * g0.x); o0.y = f2bf(v0.y * rms * g0.y);
  o0.z = f2bf(v0.z * rms * g0.z); o0.w = f2bf(v0.w * rms * g0.w);
  o1.x = f2bf(v1.x * rms * g1.x); o1.y = f2bf(v1.y * rms * g1.y);
  o1.z = f2bf(v1.z * rms * g1.z); o1.w = f2bf(v1.w * rms * g1.w);
  ushort4* orow = (ushort4*)(out + (size_t)row * DMODEL);
  orow[tid] = o0;
  orow[tid + 256] = o1;
}

// ---------------------------------------------------------------------------
// GEMM: C[M,N] = A[M,K](bf16) * Bt[N,K](bf16)^T ; m97 structure (128x128, BK=32)
// EPI 0: store bf16 [M,N]
// EPI 1: store bf16 to Vt[b,h,dh,s] layout (for attention PV operand)
// EPI 2: store f32 [M,N] = acc + resid
// ---------------------------------------------------------------------------
template <int EPI>
__global__ __launch_bounds__(256) void gemm_bt(const u16* __restrict__ A,
                                               const u16* __restrict__ Bt,
                                               void* __restrict__ C,
                                               const float* __restrict__ resid,
                                               int M, int N, int K) {
  __shared__ u16 As[128 * 32];
  __shared__ u16 Bs[128 * 32];
  const int tid = threadIdx.x;
  const int lane = tid & 63, wave = tid >> 6;
  const int m0 = blockIdx.y << 7, n0 = blockIdx.x << 7;
  const int wr = wave >> 1, wc = wave & 1;

  const f32x4 fz = {0.f, 0.f, 0.f, 0.f};
  f32x4 acc[4][4];
#pragma unroll
  for (int i = 0; i < 4; ++i)
#pragma unroll
    for (int j = 0; j < 4; ++j) acc[i][j] = fz;

  // staging: 16 chunks of 1KB (A:8, B:8); wave w does A/B chunks 2w, 2w+1
  const int cA = wave * 2;
  const int srow = cA * 16 + (lane >> 2);      // row of this lane's 16B piece
  const int scol = (lane & 3) * 8;             // bf16 col within BK=32
  const u16* gA0 = A + (size_t)(m0 + srow) * K + scol;
  const u16* gA1 = A + (size_t)(m0 + srow + 16) * K + scol;
  const u16* gB0 = Bt + (size_t)(n0 + srow) * K + scol;
  const u16* gB1 = Bt + (size_t)(n0 + srow + 16) * K + scol;
  u16* lA0 = &As[cA * 512];
  u16* lA1 = &As[cA * 512 + 512];
  u16* lB0 = &Bs[cA * 512];
  u16* lB1 = &Bs[cA * 512 + 512];

  const u16* pa = &As[(size_t)(wr * 64 + (lane & 15)) * 32 + (lane >> 4) * 8];
  const u16* pb = &Bs[(size_t)(wc * 64 + (lane & 15)) * 32 + (lane >> 4) * 8];

  for (int kt = 0; kt < K; kt += 32) {
    __syncthreads();
    gload16(gA0 + kt, lA0);
    gload16(gA1 + kt, lA1);
    gload16(gB0 + kt, lB0);
    gload16(gB1 + kt, lB1);
    __syncthreads();
    s16x8 ar[4], br[4];
#pragma unroll
    for (int m = 0; m < 4; ++m) ar[m] = *(const s16x8*)(pa + m * 16 * 32);
#pragma unroll
    for (int n = 0; n < 4; ++n) br[n] = *(const s16x8*)(pb + n * 16 * 32);
#pragma unroll
    for (int m = 0; m < 4; ++m)
#pragma unroll
      for (int n = 0; n < 4; ++n)
        acc[m][n] = __builtin_amdgcn_mfma_f32_16x16x32_bf16(ar[m], br[n],
                                                            acc[m][n], 0, 0, 0);
  }

  // C/D layout (m89-verified): col = lane&15, row = (lane>>4)*4 + reg
  const int orow = m0 + wr * 64 + ((lane >> 4) << 2);
  const int ocol = n0 + wc * 64 + (lane & 15);
  if (EPI == 0) {
    u16* O = (u16*)C;
#pragma unroll
    for (int m = 0; m < 4; ++m)
#pragma unroll
      for (int n = 0; n < 4; ++n)
#pragma unroll
        for (int r = 0; r < 4; ++r)
          O[(size_t)(orow + m * 16 + r) * N + ocol + n * 16] = f2bf(acc[m][n][r]);
  } else if (EPI == 1) {
    u16* O = (u16*)C;
#pragma unroll
    for (int m = 0; m < 4; ++m) {
      const int row = orow + m * 16;            // (b, s); r spans s..s+3
      const int b = row >> 11, s = row & 2047;
#pragma unroll
      for (int n = 0; n < 4; ++n) {
        const int col = ocol + n * 16;          // h*128 + dh
        const int hh = col >> 7, dd = col & 127;
        ushort4 o;
        o.x = f2bf(acc[m][n][0]); o.y = f2bf(acc[m][n][1]);
        o.z = f2bf(acc[m][n][2]); o.w = f2bf(acc[m][n][3]);
        *(ushort4*)(O + (((size_t)(b * NHEADS + hh) * DHEAD + dd) << 11) + s) = o;
      }
    }
  } else {
    float* O = (float*)C;
#pragma unroll
    for (int m = 0; m < 4; ++m)
#pragma unroll
      for (int n = 0; n < 4; ++n)
#pragma unroll
        for (int r = 0; r < 4; ++r) {
          const size_t idx = (size_t)(orow + m * 16 + r) * N + ocol + n * 16;
          O[idx] = acc[m][n][r] + resid[idx];
        }
  }
}

// ---------------------------------------------------------------------------
// Fused SwiGLU GEMM: U[M,N] = bf16( silu(A·B1t^T) * (A·B3t^T) )
// Block = 128x64 output; wave tile 64x32 per accumulator pair ->
// acc = 2*(4x2) frags = 64 regs (no occupancy cliff); per-K-step profile
// identical to m97: 16 MFMA, 8 ds_read_b128, 4 gload16 per wave.
// ---------------------------------------------------------------------------
__global__ __launch_bounds__(256) void gemm_swiglu(const u16* __restrict__ A,
                                                   const u16* __restrict__ B1t,
                                                   const u16* __restrict__ B3t,
                                                   u16* __restrict__ U,
                                                   int M, int N, int K) {
  __shared__ u16 As[128 * 32];
  __shared__ u16 Bs1[64 * 32];
  __shared__ u16 Bs3[64 * 32];
  const int tid = threadIdx.x;
  const int lane = tid & 63, wave = tid >> 6;
  const int m0 = blockIdx.y << 7, n0 = blockIdx.x << 6;
  const int wr = wave >> 1, wc = wave & 1;

  const f32x4 fz = {0.f, 0.f, 0.f, 0.f};
  f32x4 acc1[4][2], acc3[4][2];
#pragma unroll
  for (int i = 0; i < 4; ++i)
#pragma unroll
    for (int j = 0; j < 2; ++j) { acc1[i][j] = fz; acc3[i][j] = fz; }

  // staging: A = 8 chunks (wave w: 2w, 2w+1); B1/B3 = 4 chunks each (wave w: w)
  const int cA = wave * 2;
  const int arow = cA * 16 + (lane >> 2);
  const int brow = wave * 16 + (lane >> 2);
  const int scol = (lane & 3) * 8;
  const u16* gA0 = A + (size_t)(m0 + arow) * K + scol;
  const u16* gA1 = A + (size_t)(m0 + arow + 16) * K + scol;
  const u16* gB1 = B1t + (size_t)(n0 + brow) * K + scol;
  const u16* gB3 = B3t + (size_t)(n0 + brow) * K + scol;
  u16* lA0 = &As[cA * 512];
  u16* lA1 = &As[cA * 512 + 512];
  u16* lB1 = &Bs1[wave * 512];
  u16* lB3 = &Bs3[wave * 512];

  const u16* pa = &As[(size_t)(wr * 64 + (lane & 15)) * 32 + (lane >> 4) * 8];
  const u16* pb1 = &Bs1[(size_t)(wc * 32 + (lane & 15)) * 32 + (lane >> 4) * 8];
  const u16* pb3 = &Bs3[(size_t)(wc * 32 + (lane & 15)) * 32 + (lane >> 4) * 8];

  for (int kt = 0; kt < K; kt += 32) {
    __syncthreads();
    gload16(gA0 + kt, lA0);
    gload16(gA1 + kt, lA1);
    gload16(gB1 + kt, lB1);
    gload16(gB3 + kt, lB3);
    __syncthreads();
    s16x8 ar[4], b1[2], b3[2];
#pragma unroll
    for (int m = 0; m < 4; ++m) ar[m] = *(const s16x8*)(pa + m * 16 * 32);
#pragma unroll
    for (int n = 0; n < 2; ++n) {
      b1[n] = *(const s16x8*)(pb1 + n * 16 * 32);
      b3[n] = *(const s16x8*)(pb3 + n * 16 * 32);
    }
#pragma unroll
    for (int m = 0; m < 4; ++m)
#pragma unroll
      for (int n = 0; n < 2; ++n) {
        acc1[m][n] = __builtin_amdgcn_mfma_f32_16x16x32_bf16(ar[m], b1[n],
                                                             acc1[m][n], 0, 0, 0);
        acc3[m][n] = __builtin_amdgcn_mfma_f32_16x16x32_bf16(ar[m], b3[n],
                                                             acc3[m][n], 0, 0, 0);
      }
  }

  const int orow = m0 + wr * 64 + ((lane >> 4) << 2);
  const int ocol = n0 + wc * 32 + (lane & 15);
#pragma unroll
  for (int m = 0; m < 4; ++m)
#pragma unroll
    for (int n = 0; n < 2; ++n)
#pragma unroll
      for (int r = 0; r < 4; ++r) {
        const float a = acc1[m][n][r];
        const float u = (a / (1.f + __expf(-a))) * acc3[m][n][r];
        U[(size_t)(orow + m * 16 + r) * N + ocol + n * 16] = f2bf(u);
      }
}

// ---------------------------------------------------------------------------
// RoPE tables: cos/sin [S_LEN][64] f32
// ---------------------------------------------------------------------------
__global__ __launch_bounds__(256) void rope_table_k(float* __restrict__ tc,
                                                    float* __restrict__ ts) {
  const int idx = blockIdx.x * 256 + threadIdx.x;   // S_LEN*64 = 131072
  const int pos = idx >> 6, j = idx & 63;
  const float inv = expf(((float)(2 * j) * (1.0f / 128.0f)) * -logf(10000.0f));
  const float th = (float)pos * inv;
  tc[idx] = cosf(th);
  ts[idx] = sinf(th);
}

// RoPE apply, in place on Q and K ([NROWS][DMODEL] bf16)
__global__ __launch_bounds__(256) void rope_apply_k(u16* __restrict__ Q,
                                                    u16* __restrict__ Kb,
                                                    const float* __restrict__ tc,
                                                    const float* __restrict__ ts) {
  const int idx = blockIdx.x * 256 + threadIdx.x;   // 2 * 4096 * 16 * 64 = 2^23
  const int j = idx & 63;
  const int h = (idx >> 6) & (NHEADS - 1);
  const int row = (idx >> 10) & (NROWS - 1);
  u16* P = (idx >> 22) ? Kb : Q;
  const int s = row & (S_LEN - 1);
  const float c = tc[s * 64 + j], sn = ts[s * 64 + j];
  const size_t base = (size_t)row * DMODEL + h * DHEAD;
  const float x1 = bf2f(P[base + j]);
  const float x2 = bf2f(P[base + 64 + j]);
  P[base + j]      = f2bf(x1 * c - x2 * sn);
  P[base + 64 + j] = f2bf(x2 * c + x1 * sn);
}

// ---------------------------------------------------------------------------
// Flash attention (non-causal). Block = 4 waves, each wave owns 16 q-rows.
// Q,K: [NROWS][DMODEL] bf16 (roped); Vt: [B*H][DHEAD][S_LEN] bf16; O like Q.
// ---------------------------------------------------------------------------
__global__ __launch_bounds__(256) void attn_k(const u16* __restrict__ Q,
                                              const u16* __restrict__ Kb,
                                              const u16* __restrict__ Vt,
                                              u16* __restrict__ O) {
  __shared__ __align__(16) u16 Plds[4][16][32];   // per-wave P tile
  const int tid = threadIdx.x, lane = tid & 63, wave = tid >> 6;
  const int qt = blockIdx.x, bh = blockIdx.y;
  const int b = bh >> 4, h = bh & 15;
  const int q0 = qt * 64 + wave * 16;

  // Q fragments: A[row=lane&15][k = ks*32 + 8*(lane>>4) + j]
  const size_t qoff = (size_t)(b * S_LEN + q0 + (lane & 15)) * DMODEL +
                      h * DHEAD + (lane >> 4) * 8;
  s16x8 aq[4];
#pragma unroll
  for (int ks = 0; ks < 4; ++ks) aq[ks] = *(const s16x8*)(Q + qoff + ks * 32);

  const float scale = 0.08838834764831845f;  // 1/sqrt(128)
  const f32x4 fz = {0.f, 0.f, 0.f, 0.f};
  f32x4 ctx[8];
#pragma unroll
  for (int n = 0; n < 8; ++n) ctx[n] = fz;
  float mrow[4] = {-1e30f, -1e30f, -1e30f, -1e30f};
  float lrow[4] = {0.f, 0.f, 0.f, 0.f};

  const size_t kbase = (size_t)(b * S_LEN) * DMODEL + h * DHEAD + (lane >> 4) * 8;
  const size_t vbase = (size_t)bh * DHEAD * S_LEN + (lane >> 4) * 8;

  for (int kv = 0; kv < S_LEN; kv += 32) {
    f32x4 s0 = fz, s1 = fz;
#pragma unroll
    for (int ks = 0; ks < 4; ++ks) {
      s16x8 k0 = *(const s16x8*)(Kb + kbase + (size_t)(kv + (lane & 15)) * DMODEL + ks * 32);
      s16x8 k1 = *(const s16x8*)(Kb + kbase + (size_t)(kv + 16 + (lane & 15)) * DMODEL + ks * 32);
      s0 = __builtin_amdgcn_mfma_f32_16x16x32_bf16(aq[ks], k0, s0, 0, 0, 0);
      s1 = __builtin_amdgcn_mfma_f32_16x16x32_bf16(aq[ks], k1, s1, 0, 0, 0);
    }
    float p0[4], p1[4], corr[4];
#pragma unroll
    for (int r = 0; r < 4; ++r) {
      const float a0 = s0[r] * scale, a1 = s1[r] * scale;
      float v = fmaxf(a0, a1);
#pragma unroll
      for (int o = 1; o < 16; o <<= 1) v = fmaxf(v, __shfl_xor(v, o));
      const float nm = fmaxf(mrow[r], v);
      corr[r] = __expf(mrow[r] - nm);
      mrow[r] = nm;
      p0[r] = __expf(a0 - nm);
      p1[r] = __expf(a1 - nm);
      float rs = p0[r] + p1[r];
#pragma unroll
      for (int o = 1; o < 16; o <<= 1) rs += __shfl_xor(rs, o);
      lrow[r] = lrow[r] * corr[r] + rs;
    }
#pragma unroll
    for (int n = 0; n < 8; ++n)
#pragma unroll
      for (int r = 0; r < 4; ++r) ctx[n][r] *= corr[r];
    // redistribute P via per-wave LDS (C-layout rows -> A-layout rows)
#pragma unroll
    for (int r = 0; r < 4; ++r) {
      Plds[wave][(lane >> 4) * 4 + r][lane & 15] = f2bf(p0[r]);
      Plds[wave][(lane >> 4) * 4 + r][16 + (lane & 15)] = f2bf(p1[r]);
    }
    const s16x8 pa = *(const s16x8*)&Plds[wave][lane & 15][(lane >> 4) * 8];
#pragma unroll
    for (int n = 0; n < 8; ++n) {
      s16x8 bv = *(const s16x8*)(Vt + vbase + (size_t)(n * 16 + (lane & 15)) * S_LEN + kv);
      ctx[n] = __builtin_amdgcn_mfma_f32_16x16x32_bf16(pa, bv, ctx[n], 0, 0, 0);
    }
  }

  float inv[4];
#pragma unroll
  for (int r = 0; r < 4; ++r) inv[r] = 1.0f / lrow[r];
#pragma unroll
  for (int n = 0; n < 8; ++n)
#pragma unroll
    for (int r = 0; r < 4; ++r)
      O[(size_t)(b * S_LEN + q0 + (lane >> 4) * 4 + r) * DMODEL +
        h * DHEAD + n * 16 + (lane & 15)] = f2bf(ctx[n][r] * inv[r]);
}

// ---------------------------------------------------------------------------
extern "C" void kernel_launch(void* const* d_in, const int* in_sizes, int n_in,
                              void* d_out, int out_size, void* d_ws, size_t ws_size,
                              hipStream_t stream) {
  (void)in_sizes; (void)n_in; (void)out_size; (void)ws_size;
  const float* x  = (const float*)d_in[0];
  const float* wq = (const float*)d_in[1];
  const float* wk = (const float*)d_in[2];
  const float* wv = (const float*)d_in[3];
  const float* wo = (const float*)d_in[4];
  const float* g1 = (const float*)d_in[5];
  const float* g2 = (const float*)d_in[6];
  const float* w1 = (const float*)d_in[7];
  const float* w2 = (const float*)d_in[8];   // dict order: w1, w2, w3
  const float* w3 = (const float*)d_in[9];
  float* out = (float*)d_out;

  char* ws = (char*)d_ws;
  size_t off = 0;
  auto alloc = [&](size_t bytes) -> char* {
    char* p = ws + off;
    off += (bytes + 255) & ~(size_t)255;
    return p;
  };
  // Layout so that U (64 MB) can alias the dead WQT..KB span.
  u16* WQT = (u16*)alloc((size_t)DMODEL * DMODEL * 2);   //  8 MB
  u16* WKT = (u16*)alloc((size_t)DMODEL * DMODEL * 2);   //  8 MB
  u16* WVT = (u16*)alloc((size_t)DMODEL * DMODEL * 2);   //  8 MB
  u16* WOT = (u16*)alloc((size_t)DMODEL * DMODEL * 2);   //  8 MB
  u16* QB  = (u16*)alloc((size_t)NROWS * DMODEL * 2);    // 16 MB
  u16* KB  = (u16*)alloc((size_t)NROWS * DMODEL * 2);    // 16 MB
  u16* VT  = (u16*)alloc((size_t)NROWS * DMODEL * 2);    // 16 MB
  u16* W1T = (u16*)alloc((size_t)HID * DMODEL * 2);      // 32 MB
  u16* W3T = (u16*)alloc((size_t)HID * DMODEL * 2);      // 32 MB
  u16* W2T = (u16*)alloc((size_t)DMODEL * HID * 2);      // 32 MB
  u16* Hb  = (u16*)alloc((size_t)NROWS * DMODEL * 2);    // 16 MB (h1 / AO / h2)
  float* X1 = (float*)alloc((size_t)NROWS * DMODEL * 4); // 32 MB
  float* TC = (float*)alloc((size_t)S_LEN * 64 * 4);
  float* TS = (float*)alloc((size_t)S_LEN * 64 * 4);
  // U[4096][8192] bf16 = 64 MB aliases WQT..WOT+QB+KB (all dead by then)
  u16* U = WQT;
  u16* AO = Hb;   // attention output overwrites h1 (dead after QKV GEMMs)

  const dim3 b256(256);
  const dim3 tb(32, 8);

  rope_table_k<<<dim3(512), b256, 0, stream>>>(TC, TS);
  transpose_cvt<<<dim3(64, 64), tb, 0, stream>>>(wq, WQT, DMODEL, DMODEL);
  transpose_cvt<<<dim3(64, 64), tb, 0, stream>>>(wk, WKT, DMODEL, DMODEL);
  transpose_cvt<<<dim3(64, 64), tb, 0, stream>>>(wv, WVT, DMODEL, DMODEL);
  transpose_cvt<<<dim3(64, 64), tb, 0, stream>>>(wo, WOT, DMODEL, DMODEL);
  transpose_cvt<<<dim3(256, 64), tb, 0, stream>>>(w1, W1T, DMODEL, HID);
  transpose_cvt<<<dim3(256, 64), tb, 0, stream>>>(w3, W3T, DMODEL, HID);
  transpose_cvt<<<dim3(64, 256), tb, 0, stream>>>(w2, W2T, HID, DMODEL);

  rmsnorm_k<<<dim3(NROWS), b256, 0, stream>>>(x, g1, Hb);
  gemm_bt<0><<<dim3(16, 32), b256, 0, stream>>>(Hb, WQT, QB, nullptr, NROWS, DMODEL, DMODEL);
  gemm_bt<0><<<dim3(16, 32), b256, 0, stream>>>(Hb, WKT, KB, nullptr, NROWS, DMODEL, DMODEL);
  gemm_bt<1><<<dim3(16, 32), b256, 0, stream>>>(Hb, WVT, VT, nullptr, NROWS, DMODEL, DMODEL);
  rope_apply_k<<<dim3(32768), b256, 0, stream>>>(QB, KB, TC, TS);
  attn_k<<<dim3(32, 32), b256, 0, stream>>>(QB, KB, VT, AO);
  gemm_bt<2><<<dim3(16, 32), b256, 0, stream>>>(AO, WOT, X1, x, NROWS, DMODEL, DMODEL);

  rmsnorm_k<<<dim3(NROWS), b256, 0, stream>>>(X1, g2, Hb);
  gemm_swiglu<<<dim3(128, 32), b256, 0, stream>>>(Hb, W1T, W3T, U, NROWS, HID, DMODEL);
  gemm_bt<2><<<dim3(16, 32), b256, 0, stream>>>(U, W2T, out, X1, NROWS, DMODEL, HID);
}

// Round 5
// 1043.809 us; speedup vs baseline: 1.5863x; 1.3013x over previous
//
#include <hip/hip_runtime.h>
#include <hip/hip_bf16.h>
#include <stdint.h>

#define S_LEN  2048
#define DMODEL 2048
#define NBATCH 2
#define NHEADS 16
#define DHEAD  128
#define HID    8192
#define NROWS  4096   // NBATCH * S_LEN

typedef unsigned short u16;
typedef unsigned int   u32;
typedef __attribute__((ext_vector_type(8))) short s16x8;   // 8 bf16 = MFMA A/B frag
typedef __attribute__((ext_vector_type(4))) float f32x4;   // MFMA C/D frag

static __device__ __forceinline__ float bf2f(u16 b) {
  return __uint_as_float(((u32)b) << 16);
}
static __device__ __forceinline__ u16 f2bf(float f) {
  u32 u = __float_as_uint(f);
  return (u16)((u + 0x7fffu + ((u >> 16) & 1u)) >> 16);   // RNE
}

// async global->LDS, 16B per lane
static __device__ __forceinline__ void gload16(const void* gp, void* lp) {
  __builtin_amdgcn_global_load_lds(
      (const __attribute__((address_space(1))) void*)gp,
      (__attribute__((address_space(3))) void*)lp, 16, 0, 0);
}

// 16-lane (DPP row) rotate-butterfly reductions — VALU pipe, no LDS traffic
#define DPP_ROR(v, C) \
  __int_as_float(__builtin_amdgcn_update_dpp(0, __float_as_int(v), C, 0xf, 0xf, true))
static __device__ __forceinline__ float red16_max(float v) {
  v = fmaxf(v, DPP_ROR(v, 0x121));
  v = fmaxf(v, DPP_ROR(v, 0x122));
  v = fmaxf(v, DPP_ROR(v, 0x124));
  v = fmaxf(v, DPP_ROR(v, 0x128));
  return v;
}
static __device__ __forceinline__ float red16_sum(float v) {
  v += DPP_ROR(v, 0x121);
  v += DPP_ROR(v, 0x122);
  v += DPP_ROR(v, 0x124);
  v += DPP_ROR(v, 0x128);
  return v;
}

// ---------------------------------------------------------------------------
// Weight prep: W[K][N] f32  ->  Wt[N][K] bf16 (tiled transpose via LDS)
// ---------------------------------------------------------------------------
__global__ __launch_bounds__(256) void transpose_cvt(const float* __restrict__ W,
                                                     u16* __restrict__ Wt,
                                                     int K, int N) {
  __shared__ float tile[32][33];
  const int tx = threadIdx.x, ty = threadIdx.y;       // 32 x 8
  const int n0 = blockIdx.x * 32, k0 = blockIdx.y * 32;
#pragma unroll
  for (int i = 0; i < 4; ++i)
    tile[ty + i * 8][tx] = W[(size_t)(k0 + ty + i * 8) * N + n0 + tx];
  __syncthreads();
#pragma unroll
  for (int i = 0; i < 4; ++i)
    Wt[(size_t)(n0 + ty + i * 8) * K + k0 + tx] = f2bf(tile[tx][ty + i * 8]);
}

// ---------------------------------------------------------------------------
// RMSNorm: row of f32 [DMODEL] -> bf16, one block per row
// ---------------------------------------------------------------------------
__global__ __launch_bounds__(256) void rmsnorm_k(const float* __restrict__ x,
                                                 const float* __restrict__ g,
                                                 u16* __restrict__ out) {
  const int row = blockIdx.x;
  const int tid = threadIdx.x;
  const float4* xr = (const float4*)(x + (size_t)row * DMODEL);
  float4 v0 = xr[tid];
  float4 v1 = xr[tid + 256];
  float ss = v0.x * v0.x + v0.y * v0.y + v0.z * v0.z + v0.w * v0.w +
             v1.x * v1.x + v1.y * v1.y + v1.z * v1.z + v1.w * v1.w;
#pragma unroll
  for (int o = 1; o < 64; o <<= 1) ss += __shfl_xor(ss, o);
  __shared__ float red[4];
  if ((tid & 63) == 0) red[tid >> 6] = ss;
  __syncthreads();
  const float tot = red[0] + red[1] + red[2] + red[3];
  const float rms = rsqrtf(tot * (1.0f / DMODEL) + 1e-6f);
  const float4* gr = (const float4*)g;
  float4 g0 = gr[tid], g1 = gr[tid + 256];
  ushort4 o0, o1;
  o0.x = f2bf(v0.x * rms * g0.x); o0.y = f2bf(v0.y * rms * g0.y);
  o0.z = f2bf(v0.z * rms * g0.z); o0.w = f2bf(v0.w * rms * g0.w);
  o1.x = f2bf(v1.x * rms * g1.x); o1.y = f2bf(v1.y * rms * g1.y);
  o1.z = f2bf(v1.z * rms * g1.z); o1.w = f2bf(v1.w * rms * g1.w);
  ushort4* orow = (ushort4*)(out + (size_t)row * DMODEL);
  orow[tid] = o0;
  orow[tid + 256] = o1;
}

// ---------------------------------------------------------------------------
// GEMM: C[M,N] = A[M,K](bf16) * Bt[N,K](bf16)^T ; m97 structure (128x128, BK=32)
// EPI 0: store bf16 [M,N] (row layout)
// EPI 1: store bf16 V in granule layout VG[bh][kvblk][(s8)*128+dh][8]
// EPI 2: store f32 [M,N] = acc + resid
// EPI 3: store bf16 K in granule layout KG[bh][kvblk][(d8)*64+kv][8]
// ---------------------------------------------------------------------------
template <int EPI>
__global__ __launch_bounds__(256) void gemm_bt(const u16* __restrict__ A,
                                               const u16* __restrict__ Bt,
                                               void* __restrict__ C,
                                               const float* __restrict__ resid,
                                               int M, int N, int K) {
  __shared__ u16 As[128 * 32];
  __shared__ u16 Bs[128 * 32];
  const int tid = threadIdx.x;
  const int lane = tid & 63, wave = tid >> 6;
  const int m0 = blockIdx.y << 7, n0 = blockIdx.x << 7;
  const int wr = wave >> 1, wc = wave & 1;

  const f32x4 fz = {0.f, 0.f, 0.f, 0.f};
  f32x4 acc[4][4];
#pragma unroll
  for (int i = 0; i < 4; ++i)
#pragma unroll
    for (int j = 0; j < 4; ++j) acc[i][j] = fz;

  const int cA = wave * 2;
  const int srow = cA * 16 + (lane >> 2);
  const int scol = (lane & 3) * 8;
  const u16* gA0 = A + (size_t)(m0 + srow) * K + scol;
  const u16* gA1 = A + (size_t)(m0 + srow + 16) * K + scol;
  const u16* gB0 = Bt + (size_t)(n0 + srow) * K + scol;
  const u16* gB1 = Bt + (size_t)(n0 + srow + 16) * K + scol;
  u16* lA0 = &As[cA * 512];
  u16* lA1 = &As[cA * 512 + 512];
  u16* lB0 = &Bs[cA * 512];
  u16* lB1 = &Bs[cA * 512 + 512];

  const u16* pa = &As[(size_t)(wr * 64 + (lane & 15)) * 32 + (lane >> 4) * 8];
  const u16* pb = &Bs[(size_t)(wc * 64 + (lane & 15)) * 32 + (lane >> 4) * 8];

  for (int kt = 0; kt < K; kt += 32) {
    __syncthreads();
    gload16(gA0 + kt, lA0);
    gload16(gA1 + kt, lA1);
    gload16(gB0 + kt, lB0);
    gload16(gB1 + kt, lB1);
    __syncthreads();
    s16x8 ar[4], br[4];
#pragma unroll
    for (int m = 0; m < 4; ++m) ar[m] = *(const s16x8*)(pa + m * 16 * 32);
#pragma unroll
    for (int n = 0; n < 4; ++n) br[n] = *(const s16x8*)(pb + n * 16 * 32);
#pragma unroll
    for (int m = 0; m < 4; ++m)
#pragma unroll
      for (int n = 0; n < 4; ++n)
        acc[m][n] = __builtin_amdgcn_mfma_f32_16x16x32_bf16(ar[m], br[n],
                                                            acc[m][n], 0, 0, 0);
  }

  // C/D layout (m89-verified): col = lane&15, row = (lane>>4)*4 + reg
  const int orow = m0 + wr * 64 + ((lane >> 4) << 2);
  const int ocol = n0 + wc * 64 + (lane & 15);
  if (EPI == 0) {
    u16* O = (u16*)C;
#pragma unroll
    for (int m = 0; m < 4; ++m)
#pragma unroll
      for (int n = 0; n < 4; ++n)
#pragma unroll
        for (int r = 0; r < 4; ++r)
          O[(size_t)(orow + m * 16 + r) * N + ocol + n * 16] = f2bf(acc[m][n][r]);
  } else if (EPI == 1) {
    u16* O = (u16*)C;
#pragma unroll
    for (int m = 0; m < 4; ++m) {
      const int row = orow + m * 16;            // (b, s); r spans s..s+3
      const int b = row >> 11, s = row & 2047;
#pragma unroll
      for (int n = 0; n < 4; ++n) {
        const int col = ocol + n * 16;          // h*128 + dh
        const int hh = col >> 7, dd = col & 127;
        ushort4 o;
        o.x = f2bf(acc[m][n][0]); o.y = f2bf(acc[m][n][1]);
        o.z = f2bf(acc[m][n][2]); o.w = f2bf(acc[m][n][3]);
        const size_t addr = (size_t)((b * NHEADS + hh) * 32 + (s >> 6)) * 8192 +
                            (((s & 63) >> 3) * 128 + dd) * 8 + (s & 7);
        *(ushort4*)(O + addr) = o;
      }
    }
  } else if (EPI == 3) {
    u16* O = (u16*)C;
#pragma unroll
    for (int m = 0; m < 4; ++m) {
      const int row = orow + m * 16;
      const int b = row >> 11, s = row & 2047;
#pragma unroll
      for (int n = 0; n < 4; ++n) {
        const int col = ocol + n * 16;
        const int hh = col >> 7, dd = col & 127;
        u16* pg = O + (size_t)((b * NHEADS + hh) * 32 + (s >> 6)) * 8192 +
                  ((dd >> 3) * 64 + (s & 63)) * 8 + (dd & 7);
#pragma unroll
        for (int r = 0; r < 4; ++r) pg[r * 8] = f2bf(acc[m][n][r]);
      }
    }
  } else {
    float* O = (float*)C;
#pragma unroll
    for (int m = 0; m < 4; ++m)
#pragma unroll
      for (int n = 0; n < 4; ++n)
#pragma unroll
        for (int r = 0; r < 4; ++r) {
          const size_t idx = (size_t)(orow + m * 16 + r) * N + ocol + n * 16;
          O[idx] = acc[m][n][r] + resid[idx];
        }
  }
}

// ---------------------------------------------------------------------------
// Fused SwiGLU GEMM: U[M,N] = bf16( silu(A·B1t^T) * (A·B3t^T) ); 128x64 block
// ---------------------------------------------------------------------------
__global__ __launch_bounds__(256) void gemm_swiglu(const u16* __restrict__ A,
                                                   const u16* __restrict__ B1t,
                                                   const u16* __restrict__ B3t,
                                                   u16* __restrict__ U,
                                                   int M, int N, int K) {
  __shared__ u16 As[128 * 32];
  __shared__ u16 Bs1[64 * 32];
  __shared__ u16 Bs3[64 * 32];
  const int tid = threadIdx.x;
  const int lane = tid & 63, wave = tid >> 6;
  const int m0 = blockIdx.y << 7, n0 = blockIdx.x << 6;
  const int wr = wave >> 1, wc = wave & 1;

  const f32x4 fz = {0.f, 0.f, 0.f, 0.f};
  f32x4 acc1[4][2], acc3[4][2];
#pragma unroll
  for (int i = 0; i < 4; ++i)
#pragma unroll
    for (int j = 0; j < 2; ++j) { acc1[i][j] = fz; acc3[i][j] = fz; }

  const int cA = wave * 2;
  const int arow = cA * 16 + (lane >> 2);
  const int brow = wave * 16 + (lane >> 2);
  const int scol = (lane & 3) * 8;
  const u16* gA0 = A + (size_t)(m0 + arow) * K + scol;
  const u16* gA1 = A + (size_t)(m0 + arow + 16) * K + scol;
  const u16* gB1 = B1t + (size_t)(n0 + brow) * K + scol;
  const u16* gB3 = B3t + (size_t)(n0 + brow) * K + scol;
  u16* lA0 = &As[cA * 512];
  u16* lA1 = &As[cA * 512 + 512];
  u16* lB1 = &Bs1[wave * 512];
  u16* lB3 = &Bs3[wave * 512];

  const u16* pa = &As[(size_t)(wr * 64 + (lane & 15)) * 32 + (lane >> 4) * 8];
  const u16* pb1 = &Bs1[(size_t)(wc * 32 + (lane & 15)) * 32 + (lane >> 4) * 8];
  const u16* pb3 = &Bs3[(size_t)(wc * 32 + (lane & 15)) * 32 + (lane >> 4) * 8];

  for (int kt = 0; kt < K; kt += 32) {
    __syncthreads();
    gload16(gA0 + kt, lA0);
    gload16(gA1 + kt, lA1);
    gload16(gB1 + kt, lB1);
    gload16(gB3 + kt, lB3);
    __syncthreads();
    s16x8 ar[4], b1[2], b3[2];
#pragma unroll
    for (int m = 0; m < 4; ++m) ar[m] = *(const s16x8*)(pa + m * 16 * 32);
#pragma unroll
    for (int n = 0; n < 2; ++n) {
      b1[n] = *(const s16x8*)(pb1 + n * 16 * 32);
      b3[n] = *(const s16x8*)(pb3 + n * 16 * 32);
    }
#pragma unroll
    for (int m = 0; m < 4; ++m)
#pragma unroll
      for (int n = 0; n < 2; ++n) {
        acc1[m][n] = __builtin_amdgcn_mfma_f32_16x16x32_bf16(ar[m], b1[n],
                                                             acc1[m][n], 0, 0, 0);
        acc3[m][n] = __builtin_amdgcn_mfma_f32_16x16x32_bf16(ar[m], b3[n],
                                                             acc3[m][n], 0, 0, 0);
      }
  }

  const int orow = m0 + wr * 64 + ((lane >> 4) << 2);
  const int ocol = n0 + wc * 32 + (lane & 15);
#pragma unroll
  for (int m = 0; m < 4; ++m)
#pragma unroll
    for (int n = 0; n < 2; ++n)
#pragma unroll
      for (int r = 0; r < 4; ++r) {
        const float a = acc1[m][n][r];
        const float u = (a / (1.f + __expf(-a))) * acc3[m][n][r];
        U[(size_t)(orow + m * 16 + r) * N + ocol + n * 16] = f2bf(u);
      }
}

// ---------------------------------------------------------------------------
// RoPE tables: cos/sin [S_LEN][64] f32
// ---------------------------------------------------------------------------
__global__ __launch_bounds__(256) void rope_table_k(float* __restrict__ tc,
                                                    float* __restrict__ ts) {
  const int idx = blockIdx.x * 256 + threadIdx.x;   // S_LEN*64 = 131072
  const int pos = idx >> 6, j = idx & 63;
  const float inv = expf(((float)(2 * j) * (1.0f / 128.0f)) * -logf(10000.0f));
  const float th = (float)pos * inv;
  tc[idx] = cosf(th);
  ts[idx] = sinf(th);
}

// RoPE apply: Q in row layout [NROWS][DMODEL]; K in granule layout KG
__global__ __launch_bounds__(256) void rope_apply_k(u16* __restrict__ Q,
                                                    u16* __restrict__ KG,
                                                    const float* __restrict__ tc,
                                                    const float* __restrict__ ts) {
  const int idx = blockIdx.x * 256 + threadIdx.x;   // 2^23 total
  const int j = idx & 63;
  const int h = (idx >> 6) & (NHEADS - 1);
  const int row = (idx >> 10) & (NROWS - 1);
  const int s = row & (S_LEN - 1);
  const float c = tc[s * 64 + j], sn = ts[s * 64 + j];
  if (idx >> 22) {  // K (granule layout): pair (j, j+64) = +8 granule-cols = +4096
    const int bh = (row >> 11) * NHEADS + h;
    u16* p = KG + (size_t)(bh * 32 + (s >> 6)) * 8192 +
             ((j >> 3) * 64 + (s & 63)) * 8 + (j & 7);
    const float x1 = bf2f(p[0]);
    const float x2 = bf2f(p[4096]);
    p[0]    = f2bf(x1 * c - x2 * sn);
    p[4096] = f2bf(x2 * c + x1 * sn);
  } else {          // Q (row layout)
    const size_t base = (size_t)row * DMODEL + h * DHEAD;
    const float x1 = bf2f(Q[base + j]);
    const float x2 = bf2f(Q[base + 64 + j]);
    Q[base + j]      = f2bf(x1 * c - x2 * sn);
    Q[base + 64 + j] = f2bf(x2 * c + x1 * sn);
  }
}

// ---------------------------------------------------------------------------
// Flash attention. 4 waves x 32 q-rows = 128 q/block; KVBLK=64.
// grid = (S_LEN/128, NBATCH*NHEADS); qrow0 includes the batch offset.
// K: KG granule layout, double-buffered LDS, prefetched (counted vmcnt).
// V: VG granule layout, single LDS buffer, issue-early/consume-late.
// P: per-wave LDS granule tile with bank-permuted rows.
// ---------------------------------------------------------------------------
__global__ __launch_bounds__(256, 2) void attn_k(const u16* __restrict__ Q,
                                                 const u16* __restrict__ KG,
                                                 const u16* __restrict__ VG,
                                                 u16* __restrict__ O) {
  __shared__ __align__(16) u16 Ks[2][8192];   // 2 x 16KB (1024 granules: c*64+kv)
  __shared__ __align__(16) u16 Vs[8192];      // 16KB (1024 granules: cs*128+dh)
  __shared__ __align__(16) u16 Ps[4][2048];   // 4KB/wave (256 granules, permuted)
  const int tid = threadIdx.x, lane = tid & 63, wave = tid >> 6;
  const int g = lane >> 4, cl = lane & 15;
  const int qt = blockIdx.x, bh = blockIdx.y;
  const int b = bh >> 4, h = bh & (NHEADS - 1);
  const int qrow0 = b * S_LEN + qt * 128 + wave * 32;   // batch offset included

  // Q fragments: row = qrow0 + qs*16 + cl, d = ks*32 + g*8
  s16x8 aq[2][4];
#pragma unroll
  for (int qs = 0; qs < 2; ++qs)
#pragma unroll
    for (int ks = 0; ks < 4; ++ks)
      aq[qs][ks] = *(const s16x8*)(Q + (size_t)(qrow0 + qs * 16 + cl) * DMODEL +
                                   h * DHEAD + ks * 32 + g * 8);

  const u16* kgb = KG + (size_t)bh * 32 * 8192;
  const u16* vgb = VG + (size_t)bh * 32 * 8192;

  // wave-uniform LDS dest (HW adds lane*16B); per-lane global source
  auto stage_k = [&](int kt, int buf) {
    const u16* sp = kgb + (size_t)kt * 8192 + wave * 2048 + lane * 8;
    u16* dp = &Ks[buf][wave * 2048];
#pragma unroll
    for (int i = 0; i < 4; ++i) gload16(sp + i * 512, dp + i * 512);
  };
  auto stage_v = [&](int kt) {
    const u16* sp = vgb + (size_t)kt * 8192 + wave * 2048 + lane * 8;
    u16* dp = &Vs[wave * 2048];
#pragma unroll
    for (int i = 0; i < 4; ++i) gload16(sp + i * 512, dp + i * 512);
  };

  const float scale = 0.08838834764831845f;  // 1/sqrt(128)
  const f32x4 fz = {0.f, 0.f, 0.f, 0.f};
  f32x4 ctx[2][8];
#pragma unroll
  for (int qs = 0; qs < 2; ++qs)
#pragma unroll
    for (int n = 0; n < 8; ++n) ctx[qs][n] = fz;
  float mx[2][4], lr[2][4];
#pragma unroll
  for (int qs = 0; qs < 2; ++qs)
#pragma unroll
    for (int r = 0; r < 4; ++r) { mx[qs][r] = -1e30f; lr[qs][r] = 0.f; }

  auto body = [&](int it, int buf, bool pref) {
    stage_v(it);                         // 4 loads (waited at vmcnt(4))
    if (pref) stage_k(it + 1, buf ^ 1);  // 4 loads (waited at iter end)
    // ---- QK^T from Ks[buf] ----
    f32x4 s[2][4];
#pragma unroll
    for (int qs = 0; qs < 2; ++qs)
#pragma unroll
      for (int t = 0; t < 4; ++t) s[qs][t] = fz;
#pragma unroll
    for (int t = 0; t < 4; ++t) {
      s16x8 kf[4];
#pragma unroll
      for (int ks = 0; ks < 4; ++ks)
        kf[ks] = *(const s16x8*)(&Ks[buf][((ks * 4 + g) * 64 + t * 16 + cl) * 8]);
#pragma unroll
      for (int qs = 0; qs < 2; ++qs)
#pragma unroll
        for (int ks = 0; ks < 4; ++ks)
          s[qs][t] = __builtin_amdgcn_mfma_f32_16x16x32_bf16(aq[qs][ks], kf[ks],
                                                             s[qs][t], 0, 0, 0);
    }
    // ---- online softmax (rows = q, reduce over 16 lanes = kv cols) ----
    float corr[2][4];
#pragma unroll
    for (int qs = 0; qs < 2; ++qs)
#pragma unroll
      for (int r = 0; r < 4; ++r) {
        const float a0 = s[qs][0][r] * scale, a1 = s[qs][1][r] * scale;
        const float a2 = s[qs][2][r] * scale, a3 = s[qs][3][r] * scale;
        float v = fmaxf(fmaxf(a0, a1), fmaxf(a2, a3));
        v = red16_max(v);
        const float nm = fmaxf(mx[qs][r], v);
        const float c_ = __expf(mx[qs][r] - nm);
        mx[qs][r] = nm;
        corr[qs][r] = c_;
        const float p0 = __expf(a0 - nm), p1 = __expf(a1 - nm);
        const float p2 = __expf(a2 - nm), p3 = __expf(a3 - nm);
        float rs = (p0 + p1) + (p2 + p3);
        rs = red16_sum(rs);
        lr[qs][r] = lr[qs][r] * c_ + rs;
        // P granule = c*32 + (qs*16 + r*4 + g), c = t*2 + (cl>>3)
        const int pb = (qs * 16 + r * 4 + g) * 8 + (cl & 7) + (cl >> 3) * 256;
        Ps[wave][pb]        = f2bf(p0);
        Ps[wave][pb + 512]  = f2bf(p1);
        Ps[wave][pb + 1024] = f2bf(p2);
        Ps[wave][pb + 1536] = f2bf(p3);
      }
#pragma unroll
    for (int qs = 0; qs < 2; ++qs)
#pragma unroll
      for (int n = 0; n < 8; ++n)
#pragma unroll
        for (int r = 0; r < 4; ++r) ctx[qs][n][r] *= corr[qs][r];
    // ---- V ready (own K-prefetch may stay in flight) ----
    if (pref) asm volatile("s_waitcnt vmcnt(4)" ::: "memory");
    else      asm volatile("s_waitcnt vmcnt(0)" ::: "memory");
    __builtin_amdgcn_s_barrier();
    // ---- PV from Ps (permuted read) and Vs ----
    s16x8 pa[2][2];
#pragma unroll
    for (int qs = 0; qs < 2; ++qs)
#pragma unroll
      for (int k2 = 0; k2 < 2; ++k2)
        pa[qs][k2] = *(const s16x8*)(&Ps[wave][((k2 * 4 + g) * 32 + qs * 16 +
                                                (cl & 3) * 4 + (cl >> 2)) * 8]);
#pragma unroll
    for (int n = 0; n < 8; ++n) {
      s16x8 vf0 = *(const s16x8*)(&Vs[((g) * 128 + n * 16 + cl) * 8]);
      s16x8 vf1 = *(const s16x8*)(&Vs[((4 + g) * 128 + n * 16 + cl) * 8]);
#pragma unroll
      for (int qs = 0; qs < 2; ++qs) {
        ctx[qs][n] = __builtin_amdgcn_mfma_f32_16x16x32_bf16(pa[qs][0], vf0,
                                                             ctx[qs][n], 0, 0, 0);
        ctx[qs][n] = __builtin_amdgcn_mfma_f32_16x16x32_bf16(pa[qs][1], vf1,
                                                             ctx[qs][n], 0, 0, 0);
      }
    }
    asm volatile("s_waitcnt vmcnt(0)" ::: "memory");
    __builtin_amdgcn_s_barrier();
  };

  stage_k(0, 0);
  asm volatile("s_waitcnt vmcnt(0)" ::: "memory");
  __builtin_amdgcn_s_barrier();
#pragma unroll 1
  for (int it = 0; it < 31; ++it) body(it, it & 1, true);
  body(31, 1, false);

  // ---- epilogue ----
#pragma unroll
  for (int qs = 0; qs < 2; ++qs) {
    float inv[4];
#pragma unroll
    for (int r = 0; r < 4; ++r) inv[r] = 1.0f / lr[qs][r];
#pragma unroll
    for (int n = 0; n < 8; ++n)
#pragma unroll
      for (int r = 0; r < 4; ++r)
        O[(size_t)(qrow0 + qs * 16 + g * 4 + r) * DMODEL + h * DHEAD + n * 16 + cl] =
            f2bf(ctx[qs][n][r] * inv[r]);
  }
}

// ---------------------------------------------------------------------------
extern "C" void kernel_launch(void* const* d_in, const int* in_sizes, int n_in,
                              void* d_out, int out_size, void* d_ws, size_t ws_size,
                              hipStream_t stream) {
  (void)in_sizes; (void)n_in; (void)out_size; (void)ws_size;
  const float* x  = (const float*)d_in[0];
  const float* wq = (const float*)d_in[1];
  const float* wk = (const float*)d_in[2];
  const float* wv = (const float*)d_in[3];
  const float* wo = (const float*)d_in[4];
  const float* g1 = (const float*)d_in[5];
  const float* g2 = (const float*)d_in[6];
  const float* w1 = (const float*)d_in[7];
  const float* w2 = (const float*)d_in[8];   // dict order: w1, w2, w3
  const float* w3 = (const float*)d_in[9];
  float* out = (float*)d_out;

  char* ws = (char*)d_ws;
  size_t off = 0;
  auto alloc = [&](size_t bytes) -> char* {
    char* p = ws + off;
    off += (bytes + 255) & ~(size_t)255;
    return p;
  };
  u16* WQT = (u16*)alloc((size_t)DMODEL * DMODEL * 2);   //  8 MB
  u16* WKT = (u16*)alloc((size_t)DMODEL * DMODEL * 2);   //  8 MB
  u16* WVT = (u16*)alloc((size_t)DMODEL * DMODEL * 2);   //  8 MB
  u16* WOT = (u16*)alloc((size_t)DMODEL * DMODEL * 2);   //  8 MB
  u16* QB  = (u16*)alloc((size_t)NROWS * DMODEL * 2);    // 16 MB
  u16* KGb = (u16*)alloc((size_t)NROWS * DMODEL * 2);    // 16 MB (granule layout)
  u16* VGb = (u16*)alloc((size_t)NROWS * DMODEL * 2);    // 16 MB (granule layout)
  u16* W1T = (u16*)alloc((size_t)HID * DMODEL * 2);      // 32 MB
  u16* W3T = (u16*)alloc((size_t)HID * DMODEL * 2);      // 32 MB
  u16* W2T = (u16*)alloc((size_t)DMODEL * HID * 2);      // 32 MB
  u16* Hb  = (u16*)alloc((size_t)NROWS * DMODEL * 2);    // 16 MB (h1 / AO / h2)
  float* X1 = (float*)alloc((size_t)NROWS * DMODEL * 4); // 32 MB
  float* TC = (float*)alloc((size_t)S_LEN * 64 * 4);
  float* TS = (float*)alloc((size_t)S_LEN * 64 * 4);
  // U[4096][8192] bf16 = 64 MB aliases WQT..WOT+QB+KGb (all dead by then)
  u16* U = WQT;
  u16* AO = Hb;   // attention output overwrites h1 (dead after QKV GEMMs)

  const dim3 b256(256);
  const dim3 tb(32, 8);

  rope_table_k<<<dim3(512), b256, 0, stream>>>(TC, TS);
  transpose_cvt<<<dim3(64, 64), tb, 0, stream>>>(wq, WQT, DMODEL, DMODEL);
  transpose_cvt<<<dim3(64, 64), tb, 0, stream>>>(wk, WKT, DMODEL, DMODEL);
  transpose_cvt<<<dim3(64, 64), tb, 0, stream>>>(wv, WVT, DMODEL, DMODEL);
  transpose_cvt<<<dim3(64, 64), tb, 0, stream>>>(wo, WOT, DMODEL, DMODEL);
  transpose_cvt<<<dim3(256, 64), tb, 0, stream>>>(w1, W1T, DMODEL, HID);
  transpose_cvt<<<dim3(256, 64), tb, 0, stream>>>(w3, W3T, DMODEL, HID);
  transpose_cvt<<<dim3(64, 256), tb, 0, stream>>>(w2, W2T, HID, DMODEL);

  rmsnorm_k<<<dim3(NROWS), b256, 0, stream>>>(x, g1, Hb);
  gemm_bt<0><<<dim3(16, 32), b256, 0, stream>>>(Hb, WQT, QB, nullptr, NROWS, DMODEL, DMODEL);
  gemm_bt<3><<<dim3(16, 32), b256, 0, stream>>>(Hb, WKT, KGb, nullptr, NROWS, DMODEL, DMODEL);
  gemm_bt<1><<<dim3(16, 32), b256, 0, stream>>>(Hb, WVT, VGb, nullptr, NROWS, DMODEL, DMODEL);
  rope_apply_k<<<dim3(32768), b256, 0, stream>>>(QB, KGb, TC, TS);
  attn_k<<<dim3(16, 32), b256, 0, stream>>>(QB, KGb, VGb, AO);
  gemm_bt<2><<<dim3(16, 32), b256, 0, stream>>>(AO, WOT, X1, x, NROWS, DMODEL, DMODEL);

  rmsnorm_k<<<dim3(NROWS), b256, 0, stream>>>(X1, g2, Hb);
  gemm_swiglu<<<dim3(128, 32), b256, 0, stream>>>(Hb, W1T, W3T, U, NROWS, HID, DMODEL);
  gemm_bt<2><<<dim3(16, 32), b256, 0, stream>>>(U, W2T, out, X1, NROWS, DMODEL, HID);
}